// Round 7
// baseline (289.609 us; speedup 1.0000x reference)
//
#include <hip/hip_runtime.h>
#include <hip/hip_bf16.h>
#include <cstdint>

using bf16x8 = __attribute__((ext_vector_type(8))) short;
using f32x4  = __attribute__((ext_vector_type(4))) float;
using f32x16 = __attribute__((ext_vector_type(16))) float;

typedef const __attribute__((address_space(1))) void* gas_ptr;
typedef __attribute__((address_space(3))) void* lds_ptr;

#define M_ROWS 32768
#define PLANE ((size_t)M_ROWS * 64)

__device__ __forceinline__ short f2bf(float f) {
  unsigned u = __builtin_bit_cast(unsigned, f);
  u += 0x7fffu + ((u >> 16) & 1u);
  return (short)(u >> 16);
}

__device__ __forceinline__ unsigned pack2(float a, float b) {
  unsigned ua = __builtin_bit_cast(unsigned, a);
  ua += 0x7fffu + ((ua >> 16) & 1u);
  unsigned ub = __builtin_bit_cast(unsigned, b);
  ub += 0x7fffu + ((ub >> 16) & 1u);
  return (ua >> 16) | (ub & 0xffff0000u);
}

// ---------- f32 -> bf16 bulk convert (8 elems/thread) ----------
__global__ __launch_bounds__(256) void convert_bf16(const float* __restrict__ src,
                                                    short* __restrict__ dst, int n8) {
  int i = blockIdx.x * 256 + threadIdx.x;
  if (i >= n8) return;
  const float4* s = (const float4*)(src + (size_t)i * 8);
  float4 a = s[0], b = s[1];
  uint4 o;
  o.x = pack2(a.x, a.y); o.y = pack2(a.z, a.w);
  o.z = pack2(b.x, b.y); o.w = pack2(b.z, b.w);
  *(uint4*)(dst + (size_t)i * 8) = o;
}

// ---------- transpose + f32->bf16 convert: dst[C][R] = src[R][C] ----------
__global__ __launch_bounds__(256) void transpose_to_bf16(const float* __restrict__ src,
                                                         short* __restrict__ dst,
                                                         int R, int C) {
  int idx = blockIdx.x * 256 + threadIdx.x;
  if (idx >= R * C) return;
  int c = idx / R;
  int r = idx - c * R;
  dst[(size_t)c * R + r] = f2bf(src[(size_t)r * C + c]);
}

// ---------- GEMM (m97 structure): C = A[M][K] * Bt[N][K]^T ----------
// MODE 0: bf16 out, plane-split qkv layout [which*8+head][32768][64]
// MODE 1: f32 out row-major + bias
template <int MODE>
__global__ __launch_bounds__(256) void gemm_bt(const short* __restrict__ A,
                                               const short* __restrict__ Bt,
                                               void* __restrict__ Cp,
                                               const float* __restrict__ bias,
                                               int Mt, int N, int K) {
  __shared__ short Al[128 * 32];
  __shared__ short Bl[128 * 32];

  const int tid  = threadIdx.x;
  const int lane = tid & 63;
  const int w    = tid >> 6;
  const int c16  = lane & 15;
  const int g    = lane >> 4;
  const int wm   = (w >> 1) * 64;
  const int wn   = (w & 1) * 64;

  const int nwg = gridDim.x;
  const int bid = blockIdx.x;
  const int swz = (bid & 7) * (nwg >> 3) + (bid >> 3);
  const int mtile = swz % Mt;
  const int ntile = swz / Mt;
  const int m0 = mtile * 128;
  const int n0 = ntile * 128;

  const int rsub = lane >> 2;
  const int ksub = (lane & 3) * 8;
  const short* gA0 = A  + (size_t)(m0 + w * 16 + rsub) * K + ksub;
  const short* gA1 = A  + (size_t)(m0 + (w + 4) * 16 + rsub) * K + ksub;
  const short* gB0 = Bt + (size_t)(n0 + w * 16 + rsub) * K + ksub;
  const short* gB1 = Bt + (size_t)(n0 + (w + 4) * 16 + rsub) * K + ksub;
  short* lA0 = Al + w * 512;
  short* lA1 = Al + (w + 4) * 512;
  short* lB0 = Bl + w * 512;
  short* lB1 = Bl + (w + 4) * 512;

  f32x4 acc[4][4] = {};

  for (int k0 = 0; k0 < K; k0 += 32) {
    __builtin_amdgcn_global_load_lds((gas_ptr)(gA0 + k0), (lds_ptr)lA0, 16, 0, 0);
    __builtin_amdgcn_global_load_lds((gas_ptr)(gA1 + k0), (lds_ptr)lA1, 16, 0, 0);
    __builtin_amdgcn_global_load_lds((gas_ptr)(gB0 + k0), (lds_ptr)lB0, 16, 0, 0);
    __builtin_amdgcn_global_load_lds((gas_ptr)(gB1 + k0), (lds_ptr)lB1, 16, 0, 0);
    __syncthreads();

    bf16x8 af[4], bfr[4];
    #pragma unroll
    for (int mt = 0; mt < 4; mt++)
      af[mt] = *(const bf16x8*)&Al[(wm + mt * 16 + c16) * 32 + g * 8];
    #pragma unroll
    for (int nt = 0; nt < 4; nt++)
      bfr[nt] = *(const bf16x8*)&Bl[(wn + nt * 16 + c16) * 32 + g * 8];
    #pragma unroll
    for (int mt = 0; mt < 4; mt++)
      #pragma unroll
      for (int nt = 0; nt < 4; nt++)
        acc[mt][nt] = __builtin_amdgcn_mfma_f32_16x16x32_bf16(af[mt], bfr[nt], acc[mt][nt], 0, 0, 0);
    __syncthreads();
  }

  #pragma unroll
  for (int mt = 0; mt < 4; mt++) {
    #pragma unroll
    for (int nt = 0; nt < 4; nt++) {
      const int row = m0 + wm + mt * 16 + g * 4;
      const int col = n0 + wn + nt * 16 + c16;
      if (MODE == 1) {
        float* C = (float*)Cp;
        const float bb = bias ? bias[col] : 0.f;
        #pragma unroll
        for (int r = 0; r < 4; r++)
          C[(size_t)(row + r) * N + col] = acc[mt][nt][r] + bb;
      } else {
        // plane-split: plane = (col/512)*8 + (col/64)%8, d = col%64
        short* C = (short*)Cp + ((size_t)((col >> 9) * 8 + ((col >> 6) & 7))) * PLANE
                   + (col & 63);
        #pragma unroll
        for (int r = 0; r < 4; r++)
          C[(size_t)(row + r) * 64] = f2bf(acc[mt][nt][r]);
      }
    }
  }
}

// ---------- attention: 1 block per (b, h, fr); n_sp=256, dh=64 ----------
// 32x32x16 swapped-QK^T, online softmax. PV computed as O^T = mfma(V^T, P^T)
// so the output col = lane31 = q, making corr/inv scaling lane-local (the
// round-5/6 bug was scaling o whose q lived in the reg pattern).
// LDS: B1 (V rows then K rows, 32 KB) + VT (V^T, 32 KB) = 64 KB -> 2 blocks/CU.
__global__ __launch_bounds__(256, 2) void attn_kernel(const short* __restrict__ qkv,
                                                      short* __restrict__ attn_out) {
  __shared__ short B1[256 * 64];   // stage: V rows, then K rows (XOR-swizzled)
  __shared__ short VT[64 * 256];   // V^T [d][kv] (XOR-swizzled)

  const int tid    = threadIdx.x;
  const int lane   = tid & 63;
  const int w      = tid >> 6;
  const int lane31 = lane & 31;
  const int hi     = lane >> 5;

  const int bid = blockIdx.x;
  const int fr  = bid & 31;
  const int h   = (bid >> 5) & 7;
  const int bb  = bid >> 8;
  const size_t rowbase = (size_t)bb * 8192 + (size_t)fr * 256;
  const short* qp = qkv + (size_t)(0 + h) * PLANE + rowbase * 64;
  const short* kp = qkv + (size_t)(8 + h) * PLANE + rowbase * 64;
  const short* vp = qkv + (size_t)(16 + h) * PLANE + rowbase * 64;

  const int rl   = lane >> 3;            // row within 8-row group
  const int colb = (lane & 7) * 16;      // byte col within 128B row

  // ---- stage 1: V rows -> B1 (coalesced, source pre-swizzled) ----
  #pragma unroll
  for (int i = 0; i < 8; i++) {
    const int r = w * 64 + i * 8 + rl;
    const short* src = vp + (size_t)r * 64 + ((colb ^ ((r & 7) << 4)) >> 1);
    __builtin_amdgcn_global_load_lds((gas_ptr)src,
                                     (lds_ptr)(B1 + (w * 64 + i * 8) * 64), 16, 0, 0);
  }
  __syncthreads();

  // ---- stage 2: transpose B1 -> VT (packed u32 writes, conflict-free) ----
  {
    const int p     = tid & 127;     // kv pair index
    const int dhalf = tid >> 7;      // d half: 0 -> d 0..31, 1 -> d 32..63
    const int r0 = 2 * p, r1 = 2 * p + 1;
    #pragma unroll
    for (int i = 0; i < 4; i++) {
      const int cb = dhalf * 64 + i * 16;
      bf16x8 a = *(const bf16x8*)((const char*)B1 + r0 * 128 + (cb ^ ((r0 & 7) << 4)));
      bf16x8 b = *(const bf16x8*)((const char*)B1 + r1 * 128 + (cb ^ ((r1 & 7) << 4)));
      #pragma unroll
      for (int k = 0; k < 8; k++) {
        const int d = dhalf * 32 + i * 8 + k;
        unsigned pk = ((unsigned)(unsigned short)a[k]) |
                      (((unsigned)(unsigned short)b[k]) << 16);
        *(unsigned*)((char*)VT + d * 512 + ((4 * p) ^ ((d & 7) << 4))) = pk;
      }
    }
  }
  __syncthreads();

  // ---- stage 3: K rows -> B1 (reuse buffer) ----
  #pragma unroll
  for (int i = 0; i < 8; i++) {
    const int r = w * 64 + i * 8 + rl;
    const short* src = kp + (size_t)r * 64 + ((colb ^ ((r & 7) << 4)) >> 1);
    __builtin_amdgcn_global_load_lds((gas_ptr)src,
                                     (lds_ptr)(B1 + (w * 64 + i * 8) * 64), 16, 0, 0);
  }
  __syncthreads();

  const int swl = (lane31 & 7) << 4;  // row-XOR swizzle for this lane's reads

  for (int c = 0; c < 2; c++) {
    const int q0 = c * 128 + w * 32;       // wave's 32 q rows

    // ---- Q fragments (B operand: col = q = lane31, k = 8*hi + j) ----
    const short* qrow = qp + (size_t)(q0 + lane31) * 64;
    bf16x8 qf[4];
    #pragma unroll
    for (int ds = 0; ds < 4; ds++)
      qf[ds] = *(const bf16x8*)(qrow + ds * 16 + 8 * hi);

    f32x16 o0 = {}, o1 = {};   // O^T: col = lane31 = q, rows d (o0: 0-31, o1: 32-63)
    float m = 0.f, l = 0.f;

    #pragma unroll
    for (int kt = 0; kt < 8; kt++) {
      // ---- S^T block (32 kv x 32 q): lane owns 16 raw scores of q=lane31 ----
      f32x16 s = {};
      #pragma unroll
      for (int ds = 0; ds < 4; ds++) {
        bf16x8 kf = *(const bf16x8*)((const char*)B1 + (kt * 32 + lane31) * 128 +
                                     ((ds * 32 + 16 * hi) ^ swl));
        s = __builtin_amdgcn_mfma_f32_32x32x16_bf16(kf, qf[ds], s, 0, 0, 0);
      }

      // ---- online softmax (per q = lane31; partner lane^32 = other 16) ----
      float bm = s[0];
      #pragma unroll
      for (int r = 1; r < 16; r++) bm = fmaxf(bm, s[r]);
      bm = fmaxf(bm, __shfl_xor(bm, 32));

      if (kt == 0) {
        m = bm;
      } else {
        const float mnew = fmaxf(m, bm);
        const float corr = __expf((m - mnew) * 0.125f);
        #pragma unroll
        for (int r = 0; r < 16; r++) { o0[r] *= corr; o1[r] *= corr; }
        l *= corr;
        m = mnew;
      }

      float sl = 0.f;
      #pragma unroll
      for (int r = 0; r < 16; r++) {
        const float p = __expf((s[r] - m) * 0.125f);
        s[r] = p;
        sl += p;
      }
      l += sl + __shfl_xor(sl, 32);

      // ---- P V for this 32-kv block: two 16-kv sub-blocks ----
      #pragma unroll
      for (int mh = 0; mh < 2; mh++) {
        const int rb = mh * 8;
        unsigned u0 = pack2(s[rb + 0], s[rb + 1]);
        unsigned u1 = pack2(s[rb + 2], s[rb + 3]);
        unsigned u2 = pack2(s[rb + 4], s[rb + 5]);
        unsigned u3 = pack2(s[rb + 6], s[rb + 7]);
        int s0 = hi ? (int)u0 : (int)u2;
        int s1 = hi ? (int)u1 : (int)u3;
        int r0 = __shfl_xor(s0, 32);
        int r1 = __shfl_xor(s1, 32);
        int4 paw;
        paw.x = hi ? r0 : (int)u0;
        paw.y = hi ? r1 : (int)u1;
        paw.z = hi ? (int)u2 : r0;
        paw.w = hi ? (int)u3 : r1;
        bf16x8 pa = __builtin_bit_cast(bf16x8, paw);  // P[q=lane31][kv=8hi+j]

        const int mm = kt * 2 + mh;
        bf16x8 v0f = *(const bf16x8*)((const char*)VT + (size_t)lane31 * 512 +
                                      ((mm * 32 + 16 * hi) ^ swl));
        bf16x8 v1f = *(const bf16x8*)((const char*)VT + (size_t)(32 + lane31) * 512 +
                                      ((mm * 32 + 16 * hi) ^ swl));
        // O^T = V^T . P^T : D col = lane31 = q (2nd operand's lane axis)
        o0 = __builtin_amdgcn_mfma_f32_32x32x16_bf16(v0f, pa, o0, 0, 0, 0);
        o1 = __builtin_amdgcn_mfma_f32_32x32x16_bf16(v1f, pa, o1, 0, 0, 0);
      }
    }

    // ---- normalize (lane-local: q = lane31) + store ----
    const float inv = 1.0f / l;
    #pragma unroll
    for (int r = 0; r < 16; r++) { o0[r] *= inv; o1[r] *= inv; }

    // o0[r] -> d = (r&3) + 8*(r>>2) + 4*hi ; o1[r] -> d+32 ; row = q0+lane31
    short* orow = attn_out + (rowbase + q0 + lane31) * 512 + h * 64;
    #pragma unroll
    for (int g2 = 0; g2 < 4; g2++) {
      uint2 a, b;
      a.x = pack2(o0[4 * g2 + 0], o0[4 * g2 + 1]);
      a.y = pack2(o0[4 * g2 + 2], o0[4 * g2 + 3]);
      b.x = pack2(o1[4 * g2 + 0], o1[4 * g2 + 1]);
      b.y = pack2(o1[4 * g2 + 2], o1[4 * g2 + 3]);
      *(uint2*)(orow + 8 * g2 + 4 * hi)      = a;
      *(uint2*)(orow + 32 + 8 * g2 + 4 * hi) = b;
    }
  }
}

extern "C" void kernel_launch(void* const* d_in, const int* in_sizes, int n_in,
                              void* d_out, int out_size, void* d_ws, size_t ws_size,
                              hipStream_t stream) {
  const float* x     = (const float*)d_in[0];
  const float* w_qkv = (const float*)d_in[1];
  const float* w_out = (const float*)d_in[2];
  const float* b_out = (const float*)d_in[3];
  float* out = (float*)d_out;

  const int M = M_ROWS, DIM = 512, NQKV = 1536;

  short* wqkvT = (short*)d_ws;
  short* woutT = wqkvT + (size_t)NQKV * DIM;
  short* qkvb  = woutT + (size_t)DIM * DIM;   // 24 planes [32768][64]
  short* attnb = qkvb + (size_t)M * NQKV;
  short* xbf   = attnb;  // aliased: xbf dead before attn writes

  transpose_to_bf16<<<(DIM * NQKV + 255) / 256, 256, 0, stream>>>(w_qkv, wqkvT, DIM, NQKV);
  transpose_to_bf16<<<(DIM * DIM + 255) / 256, 256, 0, stream>>>(w_out, woutT, DIM, DIM);
  convert_bf16<<<(M * DIM / 8 + 255) / 256, 256, 0, stream>>>(x, xbf, M * DIM / 8);

  gemm_bt<0><<<(M / 128) * (NQKV / 128), 256, 0, stream>>>(xbf, wqkvT, qkvb, nullptr,
                                                           M / 128, NQKV, DIM);

  attn_kernel<<<1024, 256, 0, stream>>>(qkvb, attnb);

  gemm_bt<1><<<(M / 128) * (DIM / 128), 256, 0, stream>>>(attnb, woutT, out, b_out,
                                                          M / 128, DIM, DIM);
}

// Round 8
// 263.266 us; speedup vs baseline: 1.1001x; 1.1001x over previous
//
#include <hip/hip_runtime.h>
#include <hip/hip_bf16.h>
#include <cstdint>

using bf16x8 = __attribute__((ext_vector_type(8))) short;
using f32x4  = __attribute__((ext_vector_type(4))) float;
using f32x16 = __attribute__((ext_vector_type(16))) float;

typedef const __attribute__((address_space(1))) void* gas_ptr;
typedef __attribute__((address_space(3))) void* lds_ptr;

#define M_ROWS 32768
#define PLANE ((size_t)M_ROWS * 64)

__device__ __forceinline__ short f2bf(float f) {
  unsigned u = __builtin_bit_cast(unsigned, f);
  u += 0x7fffu + ((u >> 16) & 1u);
  return (short)(u >> 16);
}

__device__ __forceinline__ unsigned pack2(float a, float b) {
  unsigned ua = __builtin_bit_cast(unsigned, a);
  ua += 0x7fffu + ((ua >> 16) & 1u);
  unsigned ub = __builtin_bit_cast(unsigned, b);
  ub += 0x7fffu + ((ub >> 16) & 1u);
  return (ua >> 16) | (ub & 0xffff0000u);
}

// ---------- f32 -> bf16 bulk convert (8 elems/thread) ----------
__global__ __launch_bounds__(256) void convert_bf16(const float* __restrict__ src,
                                                    short* __restrict__ dst, int n8) {
  int i = blockIdx.x * 256 + threadIdx.x;
  if (i >= n8) return;
  const float4* s = (const float4*)(src + (size_t)i * 8);
  float4 a = s[0], b = s[1];
  uint4 o;
  o.x = pack2(a.x, a.y); o.y = pack2(a.z, a.w);
  o.z = pack2(b.x, b.y); o.w = pack2(b.z, b.w);
  *(uint4*)(dst + (size_t)i * 8) = o;
}

// ---------- transpose + f32->bf16 convert: dst[C][R] = src[R][C] ----------
__global__ __launch_bounds__(256) void transpose_to_bf16(const float* __restrict__ src,
                                                         short* __restrict__ dst,
                                                         int R, int C) {
  int idx = blockIdx.x * 256 + threadIdx.x;
  if (idx >= R * C) return;
  int c = idx / R;
  int r = idx - c * R;
  dst[(size_t)c * R + r] = f2bf(src[(size_t)r * C + c]);
}

// ---------- GEMM (m97 structure): C = A[M][K] * Bt[N][K]^T ----------
// MODE 0: bf16 out, plane-split qkv layout [which*8+head][32768][64]
// MODE 1: f32 out row-major + bias
template <int MODE>
__global__ __launch_bounds__(256) void gemm_bt(const short* __restrict__ A,
                                               const short* __restrict__ Bt,
                                               void* __restrict__ Cp,
                                               const float* __restrict__ bias,
                                               int Mt, int N, int K) {
  __shared__ short Al[128 * 32];
  __shared__ short Bl[128 * 32];

  const int tid  = threadIdx.x;
  const int lane = tid & 63;
  const int w    = tid >> 6;
  const int c16  = lane & 15;
  const int g    = lane >> 4;
  const int wm   = (w >> 1) * 64;
  const int wn   = (w & 1) * 64;

  const int nwg = gridDim.x;
  const int bid = blockIdx.x;
  const int swz = (bid & 7) * (nwg >> 3) + (bid >> 3);
  const int mtile = swz % Mt;
  const int ntile = swz / Mt;
  const int m0 = mtile * 128;
  const int n0 = ntile * 128;

  const int rsub = lane >> 2;
  const int ksub = (lane & 3) * 8;
  const short* gA0 = A  + (size_t)(m0 + w * 16 + rsub) * K + ksub;
  const short* gA1 = A  + (size_t)(m0 + (w + 4) * 16 + rsub) * K + ksub;
  const short* gB0 = Bt + (size_t)(n0 + w * 16 + rsub) * K + ksub;
  const short* gB1 = Bt + (size_t)(n0 + (w + 4) * 16 + rsub) * K + ksub;
  short* lA0 = Al + w * 512;
  short* lA1 = Al + (w + 4) * 512;
  short* lB0 = Bl + w * 512;
  short* lB1 = Bl + (w + 4) * 512;

  f32x4 acc[4][4] = {};

  for (int k0 = 0; k0 < K; k0 += 32) {
    __builtin_amdgcn_global_load_lds((gas_ptr)(gA0 + k0), (lds_ptr)lA0, 16, 0, 0);
    __builtin_amdgcn_global_load_lds((gas_ptr)(gA1 + k0), (lds_ptr)lA1, 16, 0, 0);
    __builtin_amdgcn_global_load_lds((gas_ptr)(gB0 + k0), (lds_ptr)lB0, 16, 0, 0);
    __builtin_amdgcn_global_load_lds((gas_ptr)(gB1 + k0), (lds_ptr)lB1, 16, 0, 0);
    __syncthreads();

    bf16x8 af[4], bfr[4];
    #pragma unroll
    for (int mt = 0; mt < 4; mt++)
      af[mt] = *(const bf16x8*)&Al[(wm + mt * 16 + c16) * 32 + g * 8];
    #pragma unroll
    for (int nt = 0; nt < 4; nt++)
      bfr[nt] = *(const bf16x8*)&Bl[(wn + nt * 16 + c16) * 32 + g * 8];
    #pragma unroll
    for (int mt = 0; mt < 4; mt++)
      #pragma unroll
      for (int nt = 0; nt < 4; nt++)
        acc[mt][nt] = __builtin_amdgcn_mfma_f32_16x16x32_bf16(af[mt], bfr[nt], acc[mt][nt], 0, 0, 0);
    __syncthreads();
  }

  #pragma unroll
  for (int mt = 0; mt < 4; mt++) {
    #pragma unroll
    for (int nt = 0; nt < 4; nt++) {
      const int row = m0 + wm + mt * 16 + g * 4;
      const int col = n0 + wn + nt * 16 + c16;
      if (MODE == 1) {
        float* C = (float*)Cp;
        const float bb = bias ? bias[col] : 0.f;
        #pragma unroll
        for (int r = 0; r < 4; r++)
          C[(size_t)(row + r) * N + col] = acc[mt][nt][r] + bb;
      } else {
        // plane-split: plane = (col/512)*8 + (col/64)%8, d = col%64
        short* C = (short*)Cp + ((size_t)((col >> 9) * 8 + ((col >> 6) & 7))) * PLANE
                   + (col & 63);
        #pragma unroll
        for (int r = 0; r < 4; r++)
          C[(size_t)(row + r) * 64] = f2bf(acc[mt][nt][r]);
      }
    }
  }
}

// ---------- attention: 1 block per (b, h, fr); n_sp=256, dh=64 ----------
// Round-7 compute structure (verified), but ALL global accesses linear:
//  - K/V reg-staged (coalesced uint4 loads) + XOR-slot ds_write (layout
//    identical to round 7's: LDS[r][s] = G[r][s ^ (r&7)])
//  - V^T built in-place in the V buffer (reads->regs, barrier, writes)
//  - O bounced through the dead K buffer, stored as 128B row segments
__global__ __launch_bounds__(256, 2) void attn_kernel(const short* __restrict__ qkv,
                                                      short* __restrict__ attn_out) {
  __shared__ short Kl[256 * 64];   // K rows (XOR-slot); later O bounce
  __shared__ short Vr[256 * 64];   // V rows (XOR-slot), then in-place VT [64][256]

  const int tid    = threadIdx.x;
  const int lane   = tid & 63;
  const int w      = tid >> 6;
  const int lane31 = lane & 31;
  const int hi     = lane >> 5;

  const int bid = blockIdx.x;
  const int fr  = bid & 31;
  const int h   = (bid >> 5) & 7;
  const int bb  = bid >> 8;
  const size_t rowbase = (size_t)bb * 8192 + (size_t)fr * 256;
  const short* qp = qkv + (size_t)(0 + h) * PLANE + rowbase * 64;
  const short* kp = qkv + (size_t)(8 + h) * PLANE + rowbase * 64;
  const short* vp = qkv + (size_t)(16 + h) * PLANE + rowbase * 64;

  // ---- stage K and V: linear global loads, XOR-slot LDS writes ----
  #pragma unroll
  for (int j = 0; j < 8; j++) {
    const int g  = j * 256 + tid;      // 16B chunk index
    const int r  = g >> 3;
    const int sl = g & 7;
    const int off = r * 128 + (((sl ^ (r & 7))) << 4);
    uint4 kc = *(const uint4*)(kp + (size_t)g * 8);
    *(uint4*)((char*)Kl + off) = kc;
    uint4 vc = *(const uint4*)(vp + (size_t)g * 8);
    *(uint4*)((char*)Vr + off) = vc;
  }
  __syncthreads();

  // ---- in-place transpose Vr: V rows -> VT [d][kv] (round-7 stage-2 math) ----
  {
    const int p     = tid & 127;     // kv pair index
    const int dhalf = tid >> 7;      // d half
    const int r0 = 2 * p, r1 = 2 * p + 1;
    bf16x8 ta[4], tb[4];
    #pragma unroll
    for (int i = 0; i < 4; i++) {
      const int cb = dhalf * 64 + i * 16;
      ta[i] = *(const bf16x8*)((const char*)Vr + r0 * 128 + (cb ^ ((r0 & 7) << 4)));
      tb[i] = *(const bf16x8*)((const char*)Vr + r1 * 128 + (cb ^ ((r1 & 7) << 4)));
    }
    __syncthreads();   // all reads done before in-place overwrite
    #pragma unroll
    for (int i = 0; i < 4; i++) {
      #pragma unroll
      for (int k = 0; k < 8; k++) {
        const int d = dhalf * 32 + i * 8 + k;
        unsigned pk = ((unsigned)(unsigned short)ta[i][k]) |
                      (((unsigned)(unsigned short)tb[i][k]) << 16);
        *(unsigned*)((char*)Vr + d * 512 + ((4 * p) ^ ((d & 7) << 4))) = pk;
      }
    }
  }
  __syncthreads();

  const int swl = (lane31 & 7) << 4;  // row-XOR swizzle for this lane's reads
  unsigned pko[2][16];                // packed O (bf16 pairs), both c chunks

  #pragma unroll
  for (int c = 0; c < 2; c++) {
    const int q0 = c * 128 + w * 32;       // wave's 32 q rows

    // ---- Q fragments (B operand: col = q = lane31, k = 8*hi + j) ----
    const short* qrow = qp + (size_t)(q0 + lane31) * 64;
    bf16x8 qf[4];
    #pragma unroll
    for (int ds = 0; ds < 4; ds++)
      qf[ds] = *(const bf16x8*)(qrow + ds * 16 + 8 * hi);

    f32x16 o0 = {}, o1 = {};   // O^T: col = lane31 = q
    float m = 0.f, l = 0.f;

    #pragma unroll
    for (int kt = 0; kt < 8; kt++) {
      // ---- S^T block (32 kv x 32 q): lane owns 16 raw scores of q=lane31 ----
      f32x16 s = {};
      #pragma unroll
      for (int ds = 0; ds < 4; ds++) {
        bf16x8 kf = *(const bf16x8*)((const char*)Kl + (kt * 32 + lane31) * 128 +
                                     ((ds * 32 + 16 * hi) ^ swl));
        s = __builtin_amdgcn_mfma_f32_32x32x16_bf16(kf, qf[ds], s, 0, 0, 0);
      }

      // ---- online softmax (per q = lane31; partner lane^32 = other 16) ----
      float bm = s[0];
      #pragma unroll
      for (int r = 1; r < 16; r++) bm = fmaxf(bm, s[r]);
      bm = fmaxf(bm, __shfl_xor(bm, 32));

      if (kt == 0) {
        m = bm;
      } else {
        const float mnew = fmaxf(m, bm);
        const float corr = __expf((m - mnew) * 0.125f);
        #pragma unroll
        for (int r = 0; r < 16; r++) { o0[r] *= corr; o1[r] *= corr; }
        l *= corr;
        m = mnew;
      }

      float sl2 = 0.f;
      #pragma unroll
      for (int r = 0; r < 16; r++) {
        const float p = __expf((s[r] - m) * 0.125f);
        s[r] = p;
        sl2 += p;
      }
      l += sl2 + __shfl_xor(sl2, 32);

      // ---- P V for this 32-kv block: two 16-kv sub-blocks ----
      #pragma unroll
      for (int mh = 0; mh < 2; mh++) {
        const int rb = mh * 8;
        unsigned u0 = pack2(s[rb + 0], s[rb + 1]);
        unsigned u1 = pack2(s[rb + 2], s[rb + 3]);
        unsigned u2 = pack2(s[rb + 4], s[rb + 5]);
        unsigned u3 = pack2(s[rb + 6], s[rb + 7]);
        int s0 = hi ? (int)u0 : (int)u2;
        int s1 = hi ? (int)u1 : (int)u3;
        int r0 = __shfl_xor(s0, 32);
        int r1 = __shfl_xor(s1, 32);
        int4 paw;
        paw.x = hi ? r0 : (int)u0;
        paw.y = hi ? r1 : (int)u1;
        paw.z = hi ? (int)u2 : r0;
        paw.w = hi ? (int)u3 : r1;
        bf16x8 pa = __builtin_bit_cast(bf16x8, paw);  // P[q=lane31][kv=8hi+j]

        const int mm = kt * 2 + mh;
        bf16x8 v0f = *(const bf16x8*)((const char*)Vr + (size_t)lane31 * 512 +
                                      ((mm * 32 + 16 * hi) ^ swl));
        bf16x8 v1f = *(const bf16x8*)((const char*)Vr + (size_t)(32 + lane31) * 512 +
                                      ((mm * 32 + 16 * hi) ^ swl));
        // O^T = V^T . P^T : D col = lane31 = q
        o0 = __builtin_amdgcn_mfma_f32_32x32x16_bf16(v0f, pa, o0, 0, 0, 0);
        o1 = __builtin_amdgcn_mfma_f32_32x32x16_bf16(v1f, pa, o1, 0, 0, 0);
      }
    }

    // ---- normalize (lane-local) + pack to bf16 pairs ----
    const float inv = 1.0f / l;
    #pragma unroll
    for (int r = 0; r < 16; r++) { o0[r] *= inv; o1[r] *= inv; }
    #pragma unroll
    for (int g2 = 0; g2 < 4; g2++) {
      pko[c][2 * g2 + 0] = pack2(o0[4 * g2 + 0], o0[4 * g2 + 1]);
      pko[c][2 * g2 + 1] = pack2(o0[4 * g2 + 2], o0[4 * g2 + 3]);
      pko[c][8 + 2 * g2 + 0] = pack2(o1[4 * g2 + 0], o1[4 * g2 + 1]);
      pko[c][8 + 2 * g2 + 1] = pack2(o1[4 * g2 + 2], o1[4 * g2 + 3]);
    }
  }

  // ---- O bounce through Kl (dead), then linear coalesced store ----
  __syncthreads();   // all waves done reading Kl/Vr
  #pragma unroll
  for (int c = 0; c < 2; c++) {
    const int row = c * 128 + w * 32 + lane31;
    const int rx  = (row & 7) << 4;
    #pragma unroll
    for (int g2 = 0; g2 < 4; g2++) {
      uint2 a, b;
      a.x = pko[c][2 * g2 + 0]; a.y = pko[c][2 * g2 + 1];
      b.x = pko[c][8 + 2 * g2 + 0]; b.y = pko[c][8 + 2 * g2 + 1];
      *(uint2*)((char*)Kl + row * 128 + ((16 * g2 + 8 * hi) ^ rx))      = a;
      *(uint2*)((char*)Kl + row * 128 + ((64 + 16 * g2 + 8 * hi) ^ rx)) = b;
    }
  }
  __syncthreads();
  #pragma unroll
  for (int j = 0; j < 8; j++) {
    const int row = j * 32 + (tid >> 3);
    const int sl  = tid & 7;
    uint4 v = *(const uint4*)((const char*)Kl + row * 128 + ((sl << 4) ^ ((row & 7) << 4)));
    *(uint4*)(attn_out + (rowbase + row) * 512 + h * 64 + sl * 8) = v;
  }
}

extern "C" void kernel_launch(void* const* d_in, const int* in_sizes, int n_in,
                              void* d_out, int out_size, void* d_ws, size_t ws_size,
                              hipStream_t stream) {
  const float* x     = (const float*)d_in[0];
  const float* w_qkv = (const float*)d_in[1];
  const float* w_out = (const float*)d_in[2];
  const float* b_out = (const float*)d_in[3];
  float* out = (float*)d_out;

  const int M = M_ROWS, DIM = 512, NQKV = 1536;

  short* wqkvT = (short*)d_ws;
  short* woutT = wqkvT + (size_t)NQKV * DIM;
  short* qkvb  = woutT + (size_t)DIM * DIM;   // 24 planes [32768][64]
  short* attnb = qkvb + (size_t)M * NQKV;
  short* xbf   = attnb;  // aliased: xbf dead before attn writes

  transpose_to_bf16<<<(DIM * NQKV + 255) / 256, 256, 0, stream>>>(w_qkv, wqkvT, DIM, NQKV);
  transpose_to_bf16<<<(DIM * DIM + 255) / 256, 256, 0, stream>>>(w_out, woutT, DIM, DIM);
  convert_bf16<<<(M * DIM / 8 + 255) / 256, 256, 0, stream>>>(x, xbf, M * DIM / 8);

  gemm_bt<0><<<(M / 128) * (NQKV / 128), 256, 0, stream>>>(xbf, wqkvT, qkvb, nullptr,
                                                           M / 128, NQKV, DIM);

  attn_kernel<<<1024, 256, 0, stream>>>(qkvb, attnb);

  gemm_bt<1><<<(M / 128) * (DIM / 128), 256, 0, stream>>>(attnb, woutT, out, b_out,
                                                          M / 128, DIM, DIM);
}

// Round 9
// 230.270 us; speedup vs baseline: 1.2577x; 1.1433x over previous
//
#include <hip/hip_runtime.h>
#include <hip/hip_bf16.h>
#include <cstdint>

using bf16x8 = __attribute__((ext_vector_type(8))) short;
using f32x4  = __attribute__((ext_vector_type(4))) float;
using f32x16 = __attribute__((ext_vector_type(16))) float;

typedef const __attribute__((address_space(1))) void* gas_ptr;
typedef __attribute__((address_space(3))) void* lds_ptr;

#define M_ROWS 32768
#define PLANE ((size_t)M_ROWS * 64)

__device__ __forceinline__ short f2bf(float f) {
  unsigned u = __builtin_bit_cast(unsigned, f);
  u += 0x7fffu + ((u >> 16) & 1u);
  return (short)(u >> 16);
}

__device__ __forceinline__ unsigned pack2(float a, float b) {
  unsigned ua = __builtin_bit_cast(unsigned, a);
  ua += 0x7fffu + ((ua >> 16) & 1u);
  unsigned ub = __builtin_bit_cast(unsigned, b);
  ub += 0x7fffu + ((ub >> 16) & 1u);
  return (ua >> 16) | (ub & 0xffff0000u);
}

// ---------- f32 -> bf16 bulk convert (8 elems/thread) ----------
__global__ __launch_bounds__(256) void convert_bf16(const float* __restrict__ src,
                                                    short* __restrict__ dst, int n8) {
  int i = blockIdx.x * 256 + threadIdx.x;
  if (i >= n8) return;
  const float4* s = (const float4*)(src + (size_t)i * 8);
  float4 a = s[0], b = s[1];
  uint4 o;
  o.x = pack2(a.x, a.y); o.y = pack2(a.z, a.w);
  o.z = pack2(b.x, b.y); o.w = pack2(b.z, b.w);
  *(uint4*)(dst + (size_t)i * 8) = o;
}

// ---------- transpose + f32->bf16 convert: dst[C][R] = src[R][C] ----------
__global__ __launch_bounds__(256) void transpose_to_bf16(const float* __restrict__ src,
                                                         short* __restrict__ dst,
                                                         int R, int C) {
  int idx = blockIdx.x * 256 + threadIdx.x;
  if (idx >= R * C) return;
  int c = idx / R;
  int r = idx - c * R;
  dst[(size_t)c * R + r] = f2bf(src[(size_t)r * C + c]);
}

// ---------- GEMM (m97 structure): C = A[M][K] * Bt[N][K]^T ----------
// MODE 0: bf16 out, plane-split qkv layout [which*8+head][32768][64]
// MODE 1: f32 out row-major + bias
template <int MODE>
__global__ __launch_bounds__(256) void gemm_bt(const short* __restrict__ A,
                                               const short* __restrict__ Bt,
                                               void* __restrict__ Cp,
                                               const float* __restrict__ bias,
                                               int Mt, int N, int K) {
  __shared__ short Al[128 * 32];
  __shared__ short Bl[128 * 32];

  const int tid  = threadIdx.x;
  const int lane = tid & 63;
  const int w    = tid >> 6;
  const int c16  = lane & 15;
  const int g    = lane >> 4;
  const int wm   = (w >> 1) * 64;
  const int wn   = (w & 1) * 64;

  const int nwg = gridDim.x;
  const int bid = blockIdx.x;
  const int swz = (bid & 7) * (nwg >> 3) + (bid >> 3);
  const int mtile = swz % Mt;
  const int ntile = swz / Mt;
  const int m0 = mtile * 128;
  const int n0 = ntile * 128;

  const int rsub = lane >> 2;
  const int ksub = (lane & 3) * 8;
  const short* gA0 = A  + (size_t)(m0 + w * 16 + rsub) * K + ksub;
  const short* gA1 = A  + (size_t)(m0 + (w + 4) * 16 + rsub) * K + ksub;
  const short* gB0 = Bt + (size_t)(n0 + w * 16 + rsub) * K + ksub;
  const short* gB1 = Bt + (size_t)(n0 + (w + 4) * 16 + rsub) * K + ksub;
  short* lA0 = Al + w * 512;
  short* lA1 = Al + (w + 4) * 512;
  short* lB0 = Bl + w * 512;
  short* lB1 = Bl + (w + 4) * 512;

  f32x4 acc[4][4] = {};

  for (int k0 = 0; k0 < K; k0 += 32) {
    __builtin_amdgcn_global_load_lds((gas_ptr)(gA0 + k0), (lds_ptr)lA0, 16, 0, 0);
    __builtin_amdgcn_global_load_lds((gas_ptr)(gA1 + k0), (lds_ptr)lA1, 16, 0, 0);
    __builtin_amdgcn_global_load_lds((gas_ptr)(gB0 + k0), (lds_ptr)lB0, 16, 0, 0);
    __builtin_amdgcn_global_load_lds((gas_ptr)(gB1 + k0), (lds_ptr)lB1, 16, 0, 0);
    __syncthreads();

    bf16x8 af[4], bfr[4];
    #pragma unroll
    for (int mt = 0; mt < 4; mt++)
      af[mt] = *(const bf16x8*)&Al[(wm + mt * 16 + c16) * 32 + g * 8];
    #pragma unroll
    for (int nt = 0; nt < 4; nt++)
      bfr[nt] = *(const bf16x8*)&Bl[(wn + nt * 16 + c16) * 32 + g * 8];
    #pragma unroll
    for (int mt = 0; mt < 4; mt++)
      #pragma unroll
      for (int nt = 0; nt < 4; nt++)
        acc[mt][nt] = __builtin_amdgcn_mfma_f32_16x16x32_bf16(af[mt], bfr[nt], acc[mt][nt], 0, 0, 0);
    __syncthreads();
  }

  #pragma unroll
  for (int mt = 0; mt < 4; mt++) {
    #pragma unroll
    for (int nt = 0; nt < 4; nt++) {
      const int row = m0 + wm + mt * 16 + g * 4;
      const int col = n0 + wn + nt * 16 + c16;
      if (MODE == 1) {
        float* C = (float*)Cp;
        const float bb = bias ? bias[col] : 0.f;
        #pragma unroll
        for (int r = 0; r < 4; r++)
          C[(size_t)(row + r) * N + col] = acc[mt][nt][r] + bb;
      } else {
        // plane-split: plane = (col/512)*8 + (col/64)%8, d = col%64
        short* C = (short*)Cp + ((size_t)((col >> 9) * 8 + ((col >> 6) & 7))) * PLANE
                   + (col & 63);
        #pragma unroll
        for (int r = 0; r < 4; r++)
          C[(size_t)(row + r) * 64] = f2bf(acc[mt][nt][r]);
      }
    }
  }
}

// ---------- attention: 1 block per (b, h, fr); n_sp=256, dh=64 ----------
// Round-8 verified compute, restructured to 512 threads / 8 waves:
// each wave owns 32 q rows (no c-loop), 2 blocks/CU -> 16 waves/CU (4/SIMD)
// to hide the online-softmax dependency chains.
__global__ __launch_bounds__(512, 4) void attn_kernel(const short* __restrict__ qkv,
                                                      short* __restrict__ attn_out) {
  __shared__ short Kl[256 * 64];   // K rows (XOR-slot); later O bounce
  __shared__ short Vr[256 * 64];   // V rows (XOR-slot), then in-place VT [64][256]

  const int tid    = threadIdx.x;
  const int lane   = tid & 63;
  const int w      = tid >> 6;      // 0..7
  const int lane31 = lane & 31;
  const int hi     = lane >> 5;

  const int bid = blockIdx.x;
  const int fr  = bid & 31;
  const int h   = (bid >> 5) & 7;
  const int bb  = bid >> 8;
  const size_t rowbase = (size_t)bb * 8192 + (size_t)fr * 256;
  const short* qp = qkv + (size_t)(0 + h) * PLANE + rowbase * 64;
  const short* kp = qkv + (size_t)(8 + h) * PLANE + rowbase * 64;
  const short* vp = qkv + (size_t)(16 + h) * PLANE + rowbase * 64;

  // ---- stage K and V: linear global loads, XOR-slot LDS writes ----
  #pragma unroll
  for (int j = 0; j < 4; j++) {
    const int g  = j * 512 + tid;      // 16B chunk index, 0..2047
    const int r  = g >> 3;
    const int sl = g & 7;
    const int off = r * 128 + ((sl ^ (r & 7)) << 4);
    uint4 kc = *(const uint4*)(kp + (size_t)g * 8);
    *(uint4*)((char*)Kl + off) = kc;
    uint4 vc = *(const uint4*)(vp + (size_t)g * 8);
    *(uint4*)((char*)Vr + off) = vc;
  }
  __syncthreads();

  // ---- in-place transpose Vr: V rows -> VT [d][kv] ----
  {
    const int p   = tid & 127;     // kv pair index
    const int grp = tid >> 7;      // d group: 16 d values each
    const int r0 = 2 * p, r1 = 2 * p + 1;
    bf16x8 ta[2], tb[2];
    #pragma unroll
    for (int i = 0; i < 2; i++) {
      const int cb = grp * 32 + i * 16;
      ta[i] = *(const bf16x8*)((const char*)Vr + r0 * 128 + (cb ^ ((r0 & 7) << 4)));
      tb[i] = *(const bf16x8*)((const char*)Vr + r1 * 128 + (cb ^ ((r1 & 7) << 4)));
    }
    __syncthreads();   // all reads done before in-place overwrite
    #pragma unroll
    for (int i = 0; i < 2; i++) {
      #pragma unroll
      for (int k = 0; k < 8; k++) {
        const int d = grp * 16 + i * 8 + k;
        unsigned pk = ((unsigned)(unsigned short)ta[i][k]) |
                      (((unsigned)(unsigned short)tb[i][k]) << 16);
        *(unsigned*)((char*)Vr + d * 512 + ((4 * p) ^ ((d & 7) << 4))) = pk;
      }
    }
  }
  __syncthreads();

  const int swl = (lane31 & 7) << 4;  // row-XOR swizzle for this lane's reads
  const int q0  = w * 32;             // wave's 32 q rows
  unsigned pko[16];                   // packed O (bf16 pairs)

  {
    // ---- Q fragments (B operand: col = q = lane31, k = 8*hi + j) ----
    const short* qrow = qp + (size_t)(q0 + lane31) * 64;
    bf16x8 qf[4];
    #pragma unroll
    for (int ds = 0; ds < 4; ds++)
      qf[ds] = *(const bf16x8*)(qrow + ds * 16 + 8 * hi);

    f32x16 o0 = {}, o1 = {};   // O^T: col = lane31 = q
    float m = 0.f, l = 0.f;

    #pragma unroll
    for (int kt = 0; kt < 8; kt++) {
      // ---- S^T block (32 kv x 32 q): lane owns 16 raw scores of q=lane31 ----
      f32x16 s = {};
      #pragma unroll
      for (int ds = 0; ds < 4; ds++) {
        bf16x8 kf = *(const bf16x8*)((const char*)Kl + (kt * 32 + lane31) * 128 +
                                     ((ds * 32 + 16 * hi) ^ swl));
        s = __builtin_amdgcn_mfma_f32_32x32x16_bf16(kf, qf[ds], s, 0, 0, 0);
      }

      // ---- online softmax (per q = lane31; partner lane^32 = other 16) ----
      float bm = s[0];
      #pragma unroll
      for (int r = 1; r < 16; r++) bm = fmaxf(bm, s[r]);
      bm = fmaxf(bm, __shfl_xor(bm, 32));

      if (kt == 0) {
        m = bm;
      } else {
        const float mnew = fmaxf(m, bm);
        const float corr = __expf((m - mnew) * 0.125f);
        #pragma unroll
        for (int r = 0; r < 16; r++) { o0[r] *= corr; o1[r] *= corr; }
        l *= corr;
        m = mnew;
      }

      float sl2 = 0.f;
      #pragma unroll
      for (int r = 0; r < 16; r++) {
        const float p = __expf((s[r] - m) * 0.125f);
        s[r] = p;
        sl2 += p;
      }
      l += sl2 + __shfl_xor(sl2, 32);

      // ---- P V for this 32-kv block: two 16-kv sub-blocks ----
      #pragma unroll
      for (int mh = 0; mh < 2; mh++) {
        const int rb = mh * 8;
        unsigned u0 = pack2(s[rb + 0], s[rb + 1]);
        unsigned u1 = pack2(s[rb + 2], s[rb + 3]);
        unsigned u2 = pack2(s[rb + 4], s[rb + 5]);
        unsigned u3 = pack2(s[rb + 6], s[rb + 7]);
        int s0 = hi ? (int)u0 : (int)u2;
        int s1 = hi ? (int)u1 : (int)u3;
        int r0 = __shfl_xor(s0, 32);
        int r1 = __shfl_xor(s1, 32);
        int4 paw;
        paw.x = hi ? r0 : (int)u0;
        paw.y = hi ? r1 : (int)u1;
        paw.z = hi ? (int)u2 : r0;
        paw.w = hi ? (int)u3 : r1;
        bf16x8 pa = __builtin_bit_cast(bf16x8, paw);  // P[q=lane31][kv=8hi+j]

        const int mm = kt * 2 + mh;
        bf16x8 v0f = *(const bf16x8*)((const char*)Vr + (size_t)lane31 * 512 +
                                      ((mm * 32 + 16 * hi) ^ swl));
        bf16x8 v1f = *(const bf16x8*)((const char*)Vr + (size_t)(32 + lane31) * 512 +
                                      ((mm * 32 + 16 * hi) ^ swl));
        // O^T = V^T . P^T : D col = lane31 = q
        o0 = __builtin_amdgcn_mfma_f32_32x32x16_bf16(v0f, pa, o0, 0, 0, 0);
        o1 = __builtin_amdgcn_mfma_f32_32x32x16_bf16(v1f, pa, o1, 0, 0, 0);
      }
    }

    // ---- normalize (lane-local) + pack to bf16 pairs ----
    const float inv = 1.0f / l;
    #pragma unroll
    for (int r = 0; r < 16; r++) { o0[r] *= inv; o1[r] *= inv; }
    #pragma unroll
    for (int g2 = 0; g2 < 4; g2++) {
      pko[2 * g2 + 0] = pack2(o0[4 * g2 + 0], o0[4 * g2 + 1]);
      pko[2 * g2 + 1] = pack2(o0[4 * g2 + 2], o0[4 * g2 + 3]);
      pko[8 + 2 * g2 + 0] = pack2(o1[4 * g2 + 0], o1[4 * g2 + 1]);
      pko[8 + 2 * g2 + 1] = pack2(o1[4 * g2 + 2], o1[4 * g2 + 3]);
    }
  }

  // ---- O bounce through Kl (dead), then linear coalesced store ----
  __syncthreads();   // all waves done reading Kl/Vr
  {
    const int row = q0 + lane31;
    const int rx  = (row & 7) << 4;
    #pragma unroll
    for (int g2 = 0; g2 < 4; g2++) {
      uint2 a, b;
      a.x = pko[2 * g2 + 0]; a.y = pko[2 * g2 + 1];
      b.x = pko[8 + 2 * g2 + 0]; b.y = pko[8 + 2 * g2 + 1];
      *(uint2*)((char*)Kl + row * 128 + ((16 * g2 + 8 * hi) ^ rx))      = a;
      *(uint2*)((char*)Kl + row * 128 + ((64 + 16 * g2 + 8 * hi) ^ rx)) = b;
    }
  }
  __syncthreads();
  #pragma unroll
  for (int j = 0; j < 4; j++) {
    const int row = j * 64 + (tid >> 3);
    const int sl  = tid & 7;
    uint4 v = *(const uint4*)((const char*)Kl + row * 128 + ((sl << 4) ^ ((row & 7) << 4)));
    *(uint4*)(attn_out + (rowbase + row) * 512 + h * 64 + sl * 8) = v;
  }
}

extern "C" void kernel_launch(void* const* d_in, const int* in_sizes, int n_in,
                              void* d_out, int out_size, void* d_ws, size_t ws_size,
                              hipStream_t stream) {
  const float* x     = (const float*)d_in[0];
  const float* w_qkv = (const float*)d_in[1];
  const float* w_out = (const float*)d_in[2];
  const float* b_out = (const float*)d_in[3];
  float* out = (float*)d_out;

  const int M = M_ROWS, DIM = 512, NQKV = 1536;

  short* wqkvT = (short*)d_ws;
  short* woutT = wqkvT + (size_t)NQKV * DIM;
  short* qkvb  = woutT + (size_t)DIM * DIM;   // 24 planes [32768][64]
  short* attnb = qkvb + (size_t)M * NQKV;
  short* xbf   = attnb;  // aliased: xbf dead before attn writes

  transpose_to_bf16<<<(DIM * NQKV + 255) / 256, 256, 0, stream>>>(w_qkv, wqkvT, DIM, NQKV);
  transpose_to_bf16<<<(DIM * DIM + 255) / 256, 256, 0, stream>>>(w_out, woutT, DIM, DIM);
  convert_bf16<<<(M * DIM / 8 + 255) / 256, 256, 0, stream>>>(x, xbf, M * DIM / 8);

  gemm_bt<0><<<(M / 128) * (NQKV / 128), 256, 0, stream>>>(xbf, wqkvT, qkvb, nullptr,
                                                           M / 128, NQKV, DIM);

  attn_kernel<<<1024, 512, 0, stream>>>(qkvb, attnb);

  gemm_bt<1><<<(M / 128) * (DIM / 128), 256, 0, stream>>>(attnb, woutT, out, b_out,
                                                          M / 128, DIM, DIM);
}

// Round 10
// 207.873 us; speedup vs baseline: 1.3932x; 1.1077x over previous
//
#include <hip/hip_runtime.h>
#include <hip/hip_bf16.h>
#include <cstdint>

using bf16x8 = __attribute__((ext_vector_type(8))) short;
using f32x4  = __attribute__((ext_vector_type(4))) float;
using f32x16 = __attribute__((ext_vector_type(16))) float;

typedef const __attribute__((address_space(1))) void* gas_ptr;
typedef __attribute__((address_space(3))) void* lds_ptr;

#define M_ROWS 32768
#define PLANE ((size_t)M_ROWS * 64)

__device__ __forceinline__ short f2bf(float f) {
  unsigned u = __builtin_bit_cast(unsigned, f);
  u += 0x7fffu + ((u >> 16) & 1u);
  return (short)(u >> 16);
}

__device__ __forceinline__ unsigned pack2(float a, float b) {
  unsigned ua = __builtin_bit_cast(unsigned, a);
  ua += 0x7fffu + ((ua >> 16) & 1u);
  unsigned ub = __builtin_bit_cast(unsigned, b);
  ub += 0x7fffu + ((ub >> 16) & 1u);
  return (ua >> 16) | (ub & 0xffff0000u);
}

// ---------- f32 -> bf16 bulk convert (8 elems/thread) ----------
__global__ __launch_bounds__(256) void convert_bf16(const float* __restrict__ src,
                                                    short* __restrict__ dst, int n8) {
  int i = blockIdx.x * 256 + threadIdx.x;
  if (i >= n8) return;
  const float4* s = (const float4*)(src + (size_t)i * 8);
  float4 a = s[0], b = s[1];
  uint4 o;
  o.x = pack2(a.x, a.y); o.y = pack2(a.z, a.w);
  o.z = pack2(b.x, b.y); o.w = pack2(b.z, b.w);
  *(uint4*)(dst + (size_t)i * 8) = o;
}

// ---------- transpose + f32->bf16 convert: dst[C][R] = src[R][C] ----------
__global__ __launch_bounds__(256) void transpose_to_bf16(const float* __restrict__ src,
                                                         short* __restrict__ dst,
                                                         int R, int C) {
  int idx = blockIdx.x * 256 + threadIdx.x;
  if (idx >= R * C) return;
  int c = idx / R;
  int r = idx - c * R;
  dst[(size_t)c * R + r] = f2bf(src[(size_t)r * C + c]);
}

// ---------- 8-phase 256x256 GEMM (T2+T3+T4+T5), K=512 fixed ----------
// C = A[M][512] * Bt[N][512]^T.  8 waves (2M x 4N), BK=64 as two K=32 halves.
// Phase = (M-quadrant x k-half) = 16 MFMAs; one 16KB half-tile staged per phase
// (2 global_load_lds/thread); vmcnt(4) only at phases 4 and 8.
// LDS swizzle: 16B-slot ^= (row>>1)&3 on both stage-source and ds_read (2-way free).
// MODE 0: bf16 out, plane-split [which*8+head][32768][64].  MODE 1: f32 + bias.
template <int MODE>
__global__ __launch_bounds__(512, 2) void gemm8p(const short* __restrict__ A,
                                                 const short* __restrict__ Bt,
                                                 void* __restrict__ Cp,
                                                 const float* __restrict__ bias,
                                                 int Mt, int N) {
  constexpr int K  = 512;
  constexpr int NT = K / 64;          // 8 K-tiles
  __shared__ short lds[65536];        // A: [0,32768) B: [32768,65536)  (128 KB)

  const int tid  = threadIdx.x;
  const int lane = tid & 63;
  const int w    = tid >> 6;          // 0..7
  const int c16  = lane & 15;
  const int g    = lane >> 4;
  const int wm   = w >> 2;            // 0..1
  const int wn   = w & 3;             // 0..3

  const int nwg = gridDim.x;
  const int bid = blockIdx.x;
  const int swz = (bid & 7) * (nwg >> 3) + (bid >> 3);
  const int mtile = swz % Mt;
  const int ntile = swz / Mt;
  const int m0 = mtile * 256;
  const int n0 = ntile * 256;

  // staging geometry: issue q covers rows q*128..q*128+127; wave w rows w*16+..
  const int stg_r = w * 16 + (lane >> 2);                       // + q*128
  const int stg_c = ((lane & 3) ^ ((lane >> 3) & 3)) * 8;       // pre-swizzled src chunk
  const short* gA = A  + (size_t)(m0 + stg_r) * K + stg_c;
  const short* gB = Bt + (size_t)(n0 + stg_r) * K + stg_c;
  short* const ldsA = lds;
  short* const ldsB = lds + 32768;
  const int stg_d = w * 512;                                    // wave-uniform LDS base

  // frag-read lane offset (swizzled): row=c16, chunk g^((c16>>1)&3)
  const int f_lane = c16 * 32 + ((g ^ ((c16 >> 1) & 3)) * 8);

  f32x4 acc[2][4][4] = {};
  bf16x8 bf[4], af[4];

#define STG_(isA, p, kh, tile) do {                                               \
    const short* _s = ((isA) ? gA : gB) + (tile) * 64 + (kh) * 32;                \
    short* _d = ((isA) ? ldsA : ldsB) + ((p) * 2 + (kh)) * 8192 + stg_d;          \
    __builtin_amdgcn_global_load_lds((gas_ptr)_s, (lds_ptr)_d, 16, 0, 0);         \
    __builtin_amdgcn_global_load_lds((gas_ptr)(_s + 128 * K), (lds_ptr)(_d + 4096), 16, 0, 0); \
  } while (0)

  // prologue: tile0 (k0,k1) + tile1 (k0) = 12 loads; wait first 8 (tile0) landed
  STG_(1, 0, 0, 0); STG_(0, 0, 0, 0);
  STG_(1, 0, 1, 0); STG_(0, 0, 1, 0);
  STG_(1, 1, 0, 1); STG_(0, 1, 0, 1);
  asm volatile("s_waitcnt vmcnt(4)" ::: "memory");
  __builtin_amdgcn_s_barrier();
  asm volatile("" ::: "memory");

#define PHASE_(p, mq, kh, LOADB, sisA, sp, skh, stile, DOVM) do {                 \
    if (LOADB) {                                                                  \
      _Pragma("unroll")                                                           \
      for (int nf = 0; nf < 4; nf++)                                              \
        bf[nf] = *(const bf16x8*)&ldsB[((p) * 2 + (kh)) * 8192 +                  \
                                       (wn * 64 + nf * 16) * 32 + f_lane];        \
    }                                                                             \
    _Pragma("unroll")                                                             \
    for (int mf = 0; mf < 4; mf++)                                                \
      af[mf] = *(const bf16x8*)&ldsA[((p) * 2 + (kh)) * 8192 +                    \
                                     (wm * 128 + (mq) * 64 + mf * 16) * 32 + f_lane]; \
    STG_(sisA, sp, skh, stile);                                                   \
    asm volatile("" ::: "memory");                                                \
    __builtin_amdgcn_s_barrier();                                                 \
    asm volatile("s_waitcnt lgkmcnt(0)" ::: "memory");                            \
    __builtin_amdgcn_sched_barrier(0);                                            \
    __builtin_amdgcn_s_setprio(1);                                                \
    _Pragma("unroll")                                                             \
    for (int mf = 0; mf < 4; mf++)                                                \
      _Pragma("unroll")                                                           \
      for (int nf = 0; nf < 4; nf++)                                              \
        acc[mq][mf][nf] = __builtin_amdgcn_mfma_f32_16x16x32_bf16(af[mf], bf[nf], \
                                                      acc[mq][mf][nf], 0, 0, 0);  \
    __builtin_amdgcn_s_setprio(0);                                                \
    if (DOVM) asm volatile("s_waitcnt vmcnt(4)" ::: "memory");                    \
    asm volatile("" ::: "memory");                                                \
    __builtin_amdgcn_s_barrier();                                                 \
    asm volatile("" ::: "memory");                                                \
  } while (0)

  for (int j = 0; j < NT / 2; j++) {
    const int u  = 2 * j;
    const int t1 = u + 1;                             // always < NT
    const int t2 = (u + 2 < NT) ? u + 2 : NT - 1;     // clamp: idempotent restage
    const int t3 = (u + 3 < NT) ? u + 3 : NT - 1;
    //       p  mq kh LB  sA sp skh stile vm
    PHASE_(0, 0, 0, 1,  1, 1, 1, t1, 0);   // compute t.Mq0.k0 ; stage A(t+1,k1)
    PHASE_(0, 1, 0, 0,  0, 1, 1, t1, 0);   //         t.Mq1.k0 ; stage B(t+1,k1)
    PHASE_(0, 0, 1, 1,  1, 0, 0, t2, 0);   //         t.Mq0.k1 ; stage A(t+2,k0)
    PHASE_(0, 1, 1, 0,  0, 0, 0, t2, 1);   //         t.Mq1.k1 ; stage B(t+2,k0); vmcnt(4)
    PHASE_(1, 0, 0, 1,  1, 0, 1, t2, 0);   //       t+1.Mq0.k0 ; stage A(t+2,k1)
    PHASE_(1, 1, 0, 0,  0, 0, 1, t2, 0);   //       t+1.Mq1.k0 ; stage B(t+2,k1)
    PHASE_(1, 0, 1, 1,  1, 1, 0, t3, 0);   //       t+1.Mq0.k1 ; stage A(t+3,k0)
    PHASE_(1, 1, 1, 0,  0, 1, 0, t3, 1);   //       t+1.Mq1.k1 ; stage B(t+3,k0); vmcnt(4)
  }
#undef PHASE_
#undef STG_

  // epilogue: D layout col = c16, row = g*4 + r (verified)
  #pragma unroll
  for (int mq = 0; mq < 2; mq++) {
    #pragma unroll
    for (int mf = 0; mf < 4; mf++) {
      #pragma unroll
      for (int nf = 0; nf < 4; nf++) {
        const int row = m0 + wm * 128 + mq * 64 + mf * 16 + g * 4;
        const int col = n0 + wn * 64 + nf * 16 + c16;
        if (MODE == 1) {
          float* C = (float*)Cp;
          const float bb = bias ? bias[col] : 0.f;
          #pragma unroll
          for (int r = 0; r < 4; r++)
            C[(size_t)(row + r) * N + col] = acc[mq][mf][nf][r] + bb;
        } else {
          short* C = (short*)Cp + ((size_t)((col >> 9) * 8 + ((col >> 6) & 7))) * PLANE
                     + (col & 63);
          #pragma unroll
          for (int r = 0; r < 4; r++)
            C[(size_t)(row + r) * 64] = f2bf(acc[mq][mf][nf][r]);
        }
      }
    }
  }
}

// ---------- attention: 1 block per (b, h, fr); n_sp=256, dh=64 ----------
// (unchanged from round 9 — verified)
__global__ __launch_bounds__(512, 4) void attn_kernel(const short* __restrict__ qkv,
                                                      short* __restrict__ attn_out) {
  __shared__ short Kl[256 * 64];   // K rows (XOR-slot); later O bounce
  __shared__ short Vr[256 * 64];   // V rows (XOR-slot), then in-place VT [64][256]

  const int tid    = threadIdx.x;
  const int lane   = tid & 63;
  const int w      = tid >> 6;      // 0..7
  const int lane31 = lane & 31;
  const int hi     = lane >> 5;

  const int bid = blockIdx.x;
  const int fr  = bid & 31;
  const int h   = (bid >> 5) & 7;
  const int bb  = bid >> 8;
  const size_t rowbase = (size_t)bb * 8192 + (size_t)fr * 256;
  const short* qp = qkv + (size_t)(0 + h) * PLANE + rowbase * 64;
  const short* kp = qkv + (size_t)(8 + h) * PLANE + rowbase * 64;
  const short* vp = qkv + (size_t)(16 + h) * PLANE + rowbase * 64;

  // ---- stage K and V: linear global loads, XOR-slot LDS writes ----
  #pragma unroll
  for (int j = 0; j < 4; j++) {
    const int g  = j * 512 + tid;      // 16B chunk index, 0..2047
    const int r  = g >> 3;
    const int sl = g & 7;
    const int off = r * 128 + ((sl ^ (r & 7)) << 4);
    uint4 kc = *(const uint4*)(kp + (size_t)g * 8);
    *(uint4*)((char*)Kl + off) = kc;
    uint4 vc = *(const uint4*)(vp + (size_t)g * 8);
    *(uint4*)((char*)Vr + off) = vc;
  }
  __syncthreads();

  // ---- in-place transpose Vr: V rows -> VT [d][kv] ----
  {
    const int p   = tid & 127;     // kv pair index
    const int grp = tid >> 7;      // d group: 16 d values each
    const int r0 = 2 * p, r1 = 2 * p + 1;
    bf16x8 ta[2], tb[2];
    #pragma unroll
    for (int i = 0; i < 2; i++) {
      const int cb = grp * 32 + i * 16;
      ta[i] = *(const bf16x8*)((const char*)Vr + r0 * 128 + (cb ^ ((r0 & 7) << 4)));
      tb[i] = *(const bf16x8*)((const char*)Vr + r1 * 128 + (cb ^ ((r1 & 7) << 4)));
    }
    __syncthreads();   // all reads done before in-place overwrite
    #pragma unroll
    for (int i = 0; i < 2; i++) {
      #pragma unroll
      for (int k = 0; k < 8; k++) {
        const int d = grp * 16 + i * 8 + k;
        unsigned pk = ((unsigned)(unsigned short)ta[i][k]) |
                      (((unsigned)(unsigned short)tb[i][k]) << 16);
        *(unsigned*)((char*)Vr + d * 512 + ((4 * p) ^ ((d & 7) << 4))) = pk;
      }
    }
  }
  __syncthreads();

  const int swl = (lane31 & 7) << 4;  // row-XOR swizzle for this lane's reads
  const int q0  = w * 32;             // wave's 32 q rows
  unsigned pko[16];                   // packed O (bf16 pairs)

  {
    // ---- Q fragments (B operand: col = q = lane31, k = 8*hi + j) ----
    const short* qrow = qp + (size_t)(q0 + lane31) * 64;
    bf16x8 qf[4];
    #pragma unroll
    for (int ds = 0; ds < 4; ds++)
      qf[ds] = *(const bf16x8*)(qrow + ds * 16 + 8 * hi);

    f32x16 o0 = {}, o1 = {};   // O^T: col = lane31 = q
    float m = 0.f, l = 0.f;

    #pragma unroll
    for (int kt = 0; kt < 8; kt++) {
      // ---- S^T block (32 kv x 32 q): lane owns 16 raw scores of q=lane31 ----
      f32x16 s = {};
      #pragma unroll
      for (int ds = 0; ds < 4; ds++) {
        bf16x8 kf = *(const bf16x8*)((const char*)Kl + (kt * 32 + lane31) * 128 +
                                     ((ds * 32 + 16 * hi) ^ swl));
        s = __builtin_amdgcn_mfma_f32_32x32x16_bf16(kf, qf[ds], s, 0, 0, 0);
      }

      // ---- online softmax (per q = lane31; partner lane^32 = other 16) ----
      float bm = s[0];
      #pragma unroll
      for (int r = 1; r < 16; r++) bm = fmaxf(bm, s[r]);
      bm = fmaxf(bm, __shfl_xor(bm, 32));

      if (kt == 0) {
        m = bm;
      } else {
        const float mnew = fmaxf(m, bm);
        const float corr = __expf((m - mnew) * 0.125f);
        #pragma unroll
        for (int r = 0; r < 16; r++) { o0[r] *= corr; o1[r] *= corr; }
        l *= corr;
        m = mnew;
      }

      float sl2 = 0.f;
      #pragma unroll
      for (int r = 0; r < 16; r++) {
        const float p = __expf((s[r] - m) * 0.125f);
        s[r] = p;
        sl2 += p;
      }
      l += sl2 + __shfl_xor(sl2, 32);

      // ---- P V for this 32-kv block: two 16-kv sub-blocks ----
      #pragma unroll
      for (int mh = 0; mh < 2; mh++) {
        const int rb = mh * 8;
        unsigned u0 = pack2(s[rb + 0], s[rb + 1]);
        unsigned u1 = pack2(s[rb + 2], s[rb + 3]);
        unsigned u2 = pack2(s[rb + 4], s[rb + 5]);
        unsigned u3 = pack2(s[rb + 6], s[rb + 7]);
        int s0 = hi ? (int)u0 : (int)u2;
        int s1 = hi ? (int)u1 : (int)u3;
        int r0 = __shfl_xor(s0, 32);
        int r1 = __shfl_xor(s1, 32);
        int4 paw;
        paw.x = hi ? r0 : (int)u0;
        paw.y = hi ? r1 : (int)u1;
        paw.z = hi ? (int)u2 : r0;
        paw.w = hi ? (int)u3 : r1;
        bf16x8 pa = __builtin_bit_cast(bf16x8, paw);  // P[q=lane31][kv=8hi+j]

        const int mm = kt * 2 + mh;
        bf16x8 v0f = *(const bf16x8*)((const char*)Vr + (size_t)lane31 * 512 +
                                      ((mm * 32 + 16 * hi) ^ swl));
        bf16x8 v1f = *(const bf16x8*)((const char*)Vr + (size_t)(32 + lane31) * 512 +
                                      ((mm * 32 + 16 * hi) ^ swl));
        // O^T = V^T . P^T : D col = lane31 = q
        o0 = __builtin_amdgcn_mfma_f32_32x32x16_bf16(v0f, pa, o0, 0, 0, 0);
        o1 = __builtin_amdgcn_mfma_f32_32x32x16_bf16(v1f, pa, o1, 0, 0, 0);
      }
    }

    // ---- normalize (lane-local) + pack to bf16 pairs ----
    const float inv = 1.0f / l;
    #pragma unroll
    for (int r = 0; r < 16; r++) { o0[r] *= inv; o1[r] *= inv; }
    #pragma unroll
    for (int g2 = 0; g2 < 4; g2++) {
      pko[2 * g2 + 0] = pack2(o0[4 * g2 + 0], o0[4 * g2 + 1]);
      pko[2 * g2 + 1] = pack2(o0[4 * g2 + 2], o0[4 * g2 + 3]);
      pko[8 + 2 * g2 + 0] = pack2(o1[4 * g2 + 0], o1[4 * g2 + 1]);
      pko[8 + 2 * g2 + 1] = pack2(o1[4 * g2 + 2], o1[4 * g2 + 3]);
    }
  }

  // ---- O bounce through Kl (dead), then linear coalesced store ----
  __syncthreads();   // all waves done reading Kl/Vr
  {
    const int row = q0 + lane31;
    const int rx  = (row & 7) << 4;
    #pragma unroll
    for (int g2 = 0; g2 < 4; g2++) {
      uint2 a, b;
      a.x = pko[2 * g2 + 0]; a.y = pko[2 * g2 + 1];
      b.x = pko[8 + 2 * g2 + 0]; b.y = pko[8 + 2 * g2 + 1];
      *(uint2*)((char*)Kl + row * 128 + ((16 * g2 + 8 * hi) ^ rx))      = a;
      *(uint2*)((char*)Kl + row * 128 + ((64 + 16 * g2 + 8 * hi) ^ rx)) = b;
    }
  }
  __syncthreads();
  #pragma unroll
  for (int j = 0; j < 4; j++) {
    const int row = j * 64 + (tid >> 3);
    const int sl  = tid & 7;
    uint4 v = *(const uint4*)((const char*)Kl + row * 128 + ((sl << 4) ^ ((row & 7) << 4)));
    *(uint4*)(attn_out + (rowbase + row) * 512 + h * 64 + sl * 8) = v;
  }
}

extern "C" void kernel_launch(void* const* d_in, const int* in_sizes, int n_in,
                              void* d_out, int out_size, void* d_ws, size_t ws_size,
                              hipStream_t stream) {
  const float* x     = (const float*)d_in[0];
  const float* w_qkv = (const float*)d_in[1];
  const float* w_out = (const float*)d_in[2];
  const float* b_out = (const float*)d_in[3];
  float* out = (float*)d_out;

  const int M = M_ROWS, DIM = 512, NQKV = 1536;

  short* wqkvT = (short*)d_ws;
  short* woutT = wqkvT + (size_t)NQKV * DIM;
  short* qkvb  = woutT + (size_t)DIM * DIM;   // 24 planes [32768][64]
  short* attnb = qkvb + (size_t)M * NQKV;
  short* xbf   = attnb;  // aliased: xbf dead before attn writes

  transpose_to_bf16<<<(DIM * NQKV + 255) / 256, 256, 0, stream>>>(w_qkv, wqkvT, DIM, NQKV);
  transpose_to_bf16<<<(DIM * DIM + 255) / 256, 256, 0, stream>>>(w_out, woutT, DIM, DIM);
  convert_bf16<<<(M * DIM / 8 + 255) / 256, 256, 0, stream>>>(x, xbf, M * DIM / 8);

  // qkv = x @ w_qkv  (8-phase 256x256, plane-split bf16 out)
  gemm8p<0><<<(M / 256) * (NQKV / 256), 512, 0, stream>>>(xbf, wqkvT, qkvb, nullptr,
                                                          M / 256, NQKV);

  attn_kernel<<<1024, 512, 0, stream>>>(qkvb, attnb);

  // out = attn @ w_out + b_out  (8-phase, f32 + bias)
  gemm8p<1><<<(M / 256) * (DIM / 256), 512, 0, stream>>>(attnb, woutT, out, b_out,
                                                         M / 256, DIM);
}